// Round 7
// baseline (136.760 us; speedup 1.0000x reference)
//
#include <hip/hip_runtime.h>
#include <hip/hip_bf16.h>

#define BATCH 8192
#define DIM 64
#define TINV 5.0f              // 1 / TEMPERATURE
#define SCALE5 7.21347520444f  // 5 * log2(e): A pre-scale so MFMA acc = log2(exp(sim/T))
#define CGT 1.01831563889f     // 1 + e^-4
#define MARGIN 0.8f
#define LGAMMA 0.5f
#define LREG 1e-4f

typedef __attribute__((ext_vector_type(8))) short short8;
typedef __attribute__((ext_vector_type(4))) float float4v;

__device__ __forceinline__ unsigned short f2bf(float f) {
    unsigned int u = __builtin_bit_cast(unsigned int, f);
    unsigned int r = (u + 0x7fffu + ((u >> 16) & 1u)) >> 16;  // round-nearest-even
    return (unsigned short)r;
}

// Phase 1: 2 rows per wave (float2/lane, 32-lane groups). Gathers ue/pe/ne,
// writes e1*SCALE5 and g = e1+e2 (bf16), pos_score / -logsigmoid / sumsq per
// row. Also zeroes total[] for phase2's atomics (stream order guarantees).
// grid: 1024 blocks x 256 thr = 4096 waves = 8192 rows. No atomics.
__global__ __launch_bounds__(256) void phase1(
    const float* __restrict__ utab,
    const float* __restrict__ itab,
    const int* __restrict__ user, const int* __restrict__ posi,
    const int* __restrict__ negi,
    unsigned short* __restrict__ e1_out, unsigned short* __restrict__ g_out,
    float* __restrict__ pos_score, float* __restrict__ row_bpr,
    float* __restrict__ row_reg, float* __restrict__ total)
{
    const int tid = blockIdx.x * 256 + threadIdx.x;
    if (tid < BATCH) total[tid] = 0.0f;   // done before phase2 launches

    const int lane = threadIdx.x & 63;
    const int wv   = tid >> 6;            // 0..4095
    const int l32  = lane & 31;
    const int r    = wv * 2 + (lane >> 5);

    const int ui = user[r], pi = posi[r], ni = negi[r];
    const float2 u = *(const float2*)&utab[(size_t)ui * DIM + l32 * 2];
    const float2 p = *(const float2*)&itab[(size_t)pi * DIM + l32 * 2];
    const float2 n = *(const float2*)&itab[(size_t)ni * DIM + l32 * 2];

    float up = u.x*p.x + u.y*p.y;
    float un = u.x*n.x + u.y*n.y;
    float uu = u.x*u.x + u.y*u.y;
    float pp = p.x*p.x + p.y*p.y;
    float nn = n.x*n.x + n.y*n.y;
    #pragma unroll
    for (int off = 1; off < 32; off <<= 1) {   // reduce within 32-lane group
        up += __shfl_xor(up, off);
        un += __shfl_xor(un, off);
        uu += __shfl_xor(uu, off);
        pp += __shfl_xor(pp, off);
        nn += __shfl_xor(nn, off);
    }
    const float ia = 1.0f / fmaxf(sqrtf(uu), 1e-12f);   // e1 = u * ia
    const float ib = 1.0f / fmaxf(sqrtf(pp), 1e-12f);   // e2 = p * ib
    const float sa = SCALE5 * ia;

    union { unsigned short h[2]; unsigned int v; } pe1, pg;
    pe1.h[0] = f2bf(u.x * sa); pe1.h[1] = f2bf(u.y * sa);
    pg.h[0]  = f2bf(u.x * ia + p.x * ib); pg.h[1] = f2bf(u.y * ia + p.y * ib);
    *(unsigned int*)&e1_out[r * DIM + l32 * 2] = pe1.v;
    *(unsigned int*)&g_out[r * DIM + l32 * 2]  = pg.v;

    if (l32 == 0) {
        const float sim = up * (ia * ib);
        pos_score[r] = __expf(sim * TINV) + __expf(fmaxf(sim - MARGIN, 0.0f) * TINV);
        const float x = up - un;   // pos - neg (raw embeddings)
        row_bpr[r] = fmaxf(-x, 0.0f) + __logf(1.0f + __expf(-fabsf(x)));
        row_reg[r] = uu + pp + nn;
    }
}

// Phase 2: total[i] = sum_j f(e1_i . g_j) via bf16 MFMA, fused epilogue.
// A pre-scaled by 5*log2e so t = acc, e = 2^t (raw v_exp_f32), and
// f = e + max(e*e^-4, 1) = max(e*(1+e^-4), e+1)   (same selector, 1 op less).
// 2-wave blocks (128 thr) so the 16-workgroup/CU cap allows 32 waves/CU.
// grid (256 stripes, 16 j-slices); each wave: 32 rows x 256 cols.
__global__ __launch_bounds__(128, 8) void phase2(
    const unsigned short* __restrict__ e1,
    const unsigned short* __restrict__ g,
    float* __restrict__ total)
{
    const int w = threadIdx.x >> 6;         // wave in block: j-half
    const int lane = threadIdx.x & 63;
    const int r0 = blockIdx.x * 32;
    const int jbase = blockIdx.y * 512 + w * 256;
    const int rowsel = lane & 15;
    const int kbase = (lane >> 4) * 8;      // A/B frag: [m=lane&15][k=quad*8+j]

    short8 a[2][2];
    #pragma unroll
    for (int rt = 0; rt < 2; rt++)
        #pragma unroll
        for (int ks = 0; ks < 2; ks++)
            a[rt][ks] = *(const short8*)&e1[(r0 + rt * 16 + rowsel) * DIM + ks * 32 + kbase];

    float rowacc[2][4];
    #pragma unroll
    for (int rt = 0; rt < 2; rt++)
        #pragma unroll
        for (int q = 0; q < 4; q++) rowacc[rt][q] = 0.0f;

    for (int it = 0; it < 4; it++) {
        const int j0 = jbase + it * 64;
        short8 b[4][2];
        #pragma unroll
        for (int ct = 0; ct < 4; ct++)
            #pragma unroll
            for (int ks = 0; ks < 2; ks++)
                b[ct][ks] = *(const short8*)&g[(j0 + ct * 16 + rowsel) * DIM + ks * 32 + kbase];

        #pragma unroll
        for (int rt = 0; rt < 2; rt++) {
            #pragma unroll
            for (int ct = 0; ct < 4; ct++) {
                float4v acc = {0.0f, 0.0f, 0.0f, 0.0f};
                acc = __builtin_amdgcn_mfma_f32_16x16x32_bf16(a[rt][0], b[ct][0], acc, 0, 0, 0);
                acc = __builtin_amdgcn_mfma_f32_16x16x32_bf16(a[rt][1], b[ct][1], acc, 0, 0, 0);
                #pragma unroll
                for (int q = 0; q < 4; q++) {
                    const float e = __builtin_amdgcn_exp2f(acc[q]);  // raw v_exp_f32
                    rowacc[rt][q] += fmaxf(e * CGT, e + 1.0f);
                }
            }
        }
    }

    // reduce across the 16 column-lanes (same lane>>4 group holds same rows)
    #pragma unroll
    for (int off = 1; off < 16; off <<= 1)
        #pragma unroll
        for (int rt = 0; rt < 2; rt++)
            #pragma unroll
            for (int q = 0; q < 4; q++)
                rowacc[rt][q] += __shfl_xor(rowacc[rt][q], off);

    if ((lane & 15) == 0) {
        const int rquad = lane >> 4;  // C/D layout: row = quad*4 + q
        #pragma unroll
        for (int rt = 0; rt < 2; rt++)
            #pragma unroll
            for (int q = 0; q < 4; q++)
                atomicAdd(&total[r0 + rt * 16 + rquad * 4 + q], rowacc[rt][q]);
    }
}

// Phase 3: final reductions -> THREE FLOAT32 outputs (bpr, reg, na).
// 1 block x 1024 threads, shuffle-reduce then LDS across 16 waves.
__global__ __launch_bounds__(1024) void phase3(
    const float* __restrict__ pos_score, const float* __restrict__ total,
    const float* __restrict__ row_bpr, const float* __restrict__ row_reg,
    float* __restrict__ out)
{
    __shared__ float rb[16], rr[16], rn[16];
    float sb = 0.0f, sr = 0.0f, sn = 0.0f;
    for (int i = threadIdx.x; i < BATCH; i += 1024) {
        sb += row_bpr[i];
        sr += row_reg[i];
        sn += -__logf(pos_score[i] / total[i] + 1e-5f);
    }
    #pragma unroll
    for (int off = 32; off; off >>= 1) {
        sb += __shfl_xor(sb, off);
        sr += __shfl_xor(sr, off);
        sn += __shfl_xor(sn, off);
    }
    const int wid = threadIdx.x >> 6;
    if ((threadIdx.x & 63) == 0) { rb[wid] = sb; rr[wid] = sr; rn[wid] = sn; }
    __syncthreads();
    if (threadIdx.x == 0) {
        float tb = 0.0f, tr = 0.0f, tn = 0.0f;
        #pragma unroll
        for (int i = 0; i < 16; i++) { tb += rb[i]; tr += rr[i]; tn += rn[i]; }
        out[0] = tb / (float)BATCH;                    // bpr
        out[1] = LREG * 0.5f * tr / (float)BATCH;      // reg
        out[2] = LGAMMA * (tn / (float)BATCH);         // na
    }
}

extern "C" void kernel_launch(void* const* d_in, const int* in_sizes, int n_in,
                              void* d_out, int out_size, void* d_ws, size_t ws_size,
                              hipStream_t stream) {
    const float* utab = (const float*)d_in[0];  // float32 [100000,64]
    const float* itab = (const float*)d_in[1];  // float32 [50000,64]
    const int* user = (const int*)d_in[2];
    const int* posi = (const int*)d_in[3];
    const int* negi = (const int*)d_in[4];

    char* ws = (char*)d_ws;
    unsigned short* e1 = (unsigned short*)ws;                              // 1 MiB
    unsigned short* g  = (unsigned short*)(ws + (size_t)BATCH * DIM * 2);  // 1 MiB
    float* pos_score   = (float*)(ws + 2 * (size_t)BATCH * DIM * 2);       // 32 KiB
    float* total       = pos_score + BATCH;                                // 32 KiB
    float* row_bpr     = total + BATCH;                                    // 32 KiB
    float* row_reg     = row_bpr + BATCH;                                  // 32 KiB

    phase1<<<1024, 256, 0, stream>>>(utab, itab, user, posi, negi,
                                     e1, g, pos_score, row_bpr, row_reg, total);
    phase2<<<dim3(256, 16), 128, 0, stream>>>(e1, g, total);
    phase3<<<1, 1024, 0, stream>>>(pos_score, total, row_bpr, row_reg,
                                   (float*)d_out);
}

// Round 8
// 121.961 us; speedup vs baseline: 1.1213x; 1.1213x over previous
//
#include <hip/hip_runtime.h>
#include <hip/hip_bf16.h>

#define BATCH 8192
#define DIM 64
#define TINV 5.0f              // 1 / TEMPERATURE
#define SCALE5 7.21347520444f  // 5 * log2(e): A pre-scale so MFMA acc = log2(exp(sim/T))
#define CGT 1.01831563889f     // 1 + e^-4
#define MARGIN 0.8f
#define LGAMMA 0.5f
#define LREG 1e-4f

typedef __attribute__((ext_vector_type(8))) short short8;
typedef __attribute__((ext_vector_type(4))) float float4v;

__device__ __forceinline__ unsigned short f2bf(float f) {
    unsigned int u = __builtin_bit_cast(unsigned int, f);
    unsigned int r = (u + 0x7fffu + ((u >> 16) & 1u)) >> 16;  // round-nearest-even
    return (unsigned short)r;
}

// Phase 1: 2 rows per wave (float2/lane, 32-lane groups). Gathers ue/pe/ne,
// writes e1*SCALE5 and g = e1+e2 (bf16), pos_score / -logsigmoid / sumsq per
// row. Also zeroes total[] for phase2's atomics (stream order guarantees).
// grid: 1024 blocks x 256 thr = 4096 waves = 8192 rows. No atomics.
__global__ __launch_bounds__(256) void phase1(
    const float* __restrict__ utab,
    const float* __restrict__ itab,
    const int* __restrict__ user, const int* __restrict__ posi,
    const int* __restrict__ negi,
    unsigned short* __restrict__ e1_out, unsigned short* __restrict__ g_out,
    float* __restrict__ pos_score, float* __restrict__ row_bpr,
    float* __restrict__ row_reg, float* __restrict__ total)
{
    const int tid = blockIdx.x * 256 + threadIdx.x;
    if (tid < BATCH) total[tid] = 0.0f;   // done before phase2 launches

    const int lane = threadIdx.x & 63;
    const int wv   = tid >> 6;            // 0..4095
    const int l32  = lane & 31;
    const int r    = wv * 2 + (lane >> 5);

    const int ui = user[r], pi = posi[r], ni = negi[r];
    const float2 u = *(const float2*)&utab[(size_t)ui * DIM + l32 * 2];
    const float2 p = *(const float2*)&itab[(size_t)pi * DIM + l32 * 2];
    const float2 n = *(const float2*)&itab[(size_t)ni * DIM + l32 * 2];

    float up = u.x*p.x + u.y*p.y;
    float un = u.x*n.x + u.y*n.y;
    float uu = u.x*u.x + u.y*u.y;
    float pp = p.x*p.x + p.y*p.y;
    float nn = n.x*n.x + n.y*n.y;
    #pragma unroll
    for (int off = 1; off < 32; off <<= 1) {   // reduce within 32-lane group
        up += __shfl_xor(up, off);
        un += __shfl_xor(un, off);
        uu += __shfl_xor(uu, off);
        pp += __shfl_xor(pp, off);
        nn += __shfl_xor(nn, off);
    }
    const float ia = 1.0f / fmaxf(sqrtf(uu), 1e-12f);   // e1 = u * ia
    const float ib = 1.0f / fmaxf(sqrtf(pp), 1e-12f);   // e2 = p * ib
    const float sa = SCALE5 * ia;

    union { unsigned short h[2]; unsigned int v; } pe1, pg;
    pe1.h[0] = f2bf(u.x * sa); pe1.h[1] = f2bf(u.y * sa);
    pg.h[0]  = f2bf(u.x * ia + p.x * ib); pg.h[1] = f2bf(u.y * ia + p.y * ib);
    *(unsigned int*)&e1_out[r * DIM + l32 * 2] = pe1.v;
    *(unsigned int*)&g_out[r * DIM + l32 * 2]  = pg.v;

    if (l32 == 0) {
        const float sim = up * (ia * ib);
        pos_score[r] = __expf(sim * TINV) + __expf(fmaxf(sim - MARGIN, 0.0f) * TINV);
        const float x = up - un;   // pos - neg (raw embeddings)
        row_bpr[r] = fmaxf(-x, 0.0f) + __logf(1.0f + __expf(-fabsf(x)));
        row_reg[r] = uu + pp + nn;
    }
}

// Phase 2: total[i] = sum_j f(e1_i . g_j) via bf16 MFMA, fused epilogue.
// A pre-scaled by 5*log2e so t = acc, e = 2^t (raw v_exp_f32), and
// f = e + max(e*e^-4, 1) = max(e*(1+e^-4), e+1)   (same selector, 1 op less).
// 2-wave blocks (128 thr): 16-wg/CU cap allows 32 waves/CU. launch_bounds
// min-waves=4 (NOT 8: that clamps to 32 VGPRs and spills b-frags to scratch
// -> 43 MB HBM writes, R7 regression).
// grid (256 stripes, 16 j-slices); each wave: 32 rows x 256 cols.
__global__ __launch_bounds__(128, 4) void phase2(
    const unsigned short* __restrict__ e1,
    const unsigned short* __restrict__ g,
    float* __restrict__ total)
{
    const int w = threadIdx.x >> 6;         // wave in block: j-half
    const int lane = threadIdx.x & 63;
    const int r0 = blockIdx.x * 32;
    const int jbase = blockIdx.y * 512 + w * 256;
    const int rowsel = lane & 15;
    const int kbase = (lane >> 4) * 8;      // A/B frag: [m=lane&15][k=quad*8+j]

    short8 a[2][2];
    #pragma unroll
    for (int rt = 0; rt < 2; rt++)
        #pragma unroll
        for (int ks = 0; ks < 2; ks++)
            a[rt][ks] = *(const short8*)&e1[(r0 + rt * 16 + rowsel) * DIM + ks * 32 + kbase];

    float rowacc[2][4];
    #pragma unroll
    for (int rt = 0; rt < 2; rt++)
        #pragma unroll
        for (int q = 0; q < 4; q++) rowacc[rt][q] = 0.0f;

    for (int it = 0; it < 4; it++) {
        const int j0 = jbase + it * 64;
        short8 b[4][2];
        #pragma unroll
        for (int ct = 0; ct < 4; ct++)
            #pragma unroll
            for (int ks = 0; ks < 2; ks++)
                b[ct][ks] = *(const short8*)&g[(j0 + ct * 16 + rowsel) * DIM + ks * 32 + kbase];

        #pragma unroll
        for (int rt = 0; rt < 2; rt++) {
            #pragma unroll
            for (int ct = 0; ct < 4; ct++) {
                float4v acc = {0.0f, 0.0f, 0.0f, 0.0f};
                acc = __builtin_amdgcn_mfma_f32_16x16x32_bf16(a[rt][0], b[ct][0], acc, 0, 0, 0);
                acc = __builtin_amdgcn_mfma_f32_16x16x32_bf16(a[rt][1], b[ct][1], acc, 0, 0, 0);
                #pragma unroll
                for (int q = 0; q < 4; q++) {
                    const float e = __builtin_amdgcn_exp2f(acc[q]);  // raw v_exp_f32
                    rowacc[rt][q] += fmaxf(e * CGT, e + 1.0f);
                }
            }
        }
    }

    // reduce across the 16 column-lanes (same lane>>4 group holds same rows)
    #pragma unroll
    for (int off = 1; off < 16; off <<= 1)
        #pragma unroll
        for (int rt = 0; rt < 2; rt++)
            #pragma unroll
            for (int q = 0; q < 4; q++)
                rowacc[rt][q] += __shfl_xor(rowacc[rt][q], off);

    if ((lane & 15) == 0) {
        const int rquad = lane >> 4;  // C/D layout: row = quad*4 + q
        #pragma unroll
        for (int rt = 0; rt < 2; rt++)
            #pragma unroll
            for (int q = 0; q < 4; q++)
                atomicAdd(&total[r0 + rt * 16 + rquad * 4 + q], rowacc[rt][q]);
    }
}

// Phase 3: final reductions -> THREE FLOAT32 outputs (bpr, reg, na).
// 1 block x 1024 threads, shuffle-reduce then LDS across 16 waves.
__global__ __launch_bounds__(1024) void phase3(
    const float* __restrict__ pos_score, const float* __restrict__ total,
    const float* __restrict__ row_bpr, const float* __restrict__ row_reg,
    float* __restrict__ out)
{
    __shared__ float rb[16], rr[16], rn[16];
    float sb = 0.0f, sr = 0.0f, sn = 0.0f;
    for (int i = threadIdx.x; i < BATCH; i += 1024) {
        sb += row_bpr[i];
        sr += row_reg[i];
        sn += -__logf(pos_score[i] / total[i] + 1e-5f);
    }
    #pragma unroll
    for (int off = 32; off; off >>= 1) {
        sb += __shfl_xor(sb, off);
        sr += __shfl_xor(sr, off);
        sn += __shfl_xor(sn, off);
    }
    const int wid = threadIdx.x >> 6;
    if ((threadIdx.x & 63) == 0) { rb[wid] = sb; rr[wid] = sr; rn[wid] = sn; }
    __syncthreads();
    if (threadIdx.x == 0) {
        float tb = 0.0f, tr = 0.0f, tn = 0.0f;
        #pragma unroll
        for (int i = 0; i < 16; i++) { tb += rb[i]; tr += rr[i]; tn += rn[i]; }
        out[0] = tb / (float)BATCH;                    // bpr
        out[1] = LREG * 0.5f * tr / (float)BATCH;      // reg
        out[2] = LGAMMA * (tn / (float)BATCH);         // na
    }
}

extern "C" void kernel_launch(void* const* d_in, const int* in_sizes, int n_in,
                              void* d_out, int out_size, void* d_ws, size_t ws_size,
                              hipStream_t stream) {
    const float* utab = (const float*)d_in[0];  // float32 [100000,64]
    const float* itab = (const float*)d_in[1];  // float32 [50000,64]
    const int* user = (const int*)d_in[2];
    const int* posi = (const int*)d_in[3];
    const int* negi = (const int*)d_in[4];

    char* ws = (char*)d_ws;
    unsigned short* e1 = (unsigned short*)ws;                              // 1 MiB
    unsigned short* g  = (unsigned short*)(ws + (size_t)BATCH * DIM * 2);  // 1 MiB
    float* pos_score   = (float*)(ws + 2 * (size_t)BATCH * DIM * 2);       // 32 KiB
    float* total       = pos_score + BATCH;                                // 32 KiB
    float* row_bpr     = total + BATCH;                                    // 32 KiB
    float* row_reg     = row_bpr + BATCH;                                  // 32 KiB

    phase1<<<1024, 256, 0, stream>>>(utab, itab, user, posi, negi,
                                     e1, g, pos_score, row_bpr, row_reg, total);
    phase2<<<dim3(256, 16), 128, 0, stream>>>(e1, g, total);
    phase3<<<1, 1024, 0, stream>>>(pos_score, total, row_bpr, row_reg,
                                   (float*)d_out);
}

// Round 9
// 103.663 us; speedup vs baseline: 1.3193x; 1.1765x over previous
//
#include <hip/hip_runtime.h>
#include <hip/hip_bf16.h>

#define BATCH 8192
#define DIM 64
#define TINV 5.0f              // 1 / TEMPERATURE
#define SCALE5 7.21347520444f  // 5 * log2(e): A pre-scale so MFMA acc = log2(exp(sim/T))
#define CGT 1.01831563889f     // 1 + e^-4
#define MARGIN 0.8f
#define LGAMMA 0.5f
#define LREG 1e-4f

typedef __attribute__((ext_vector_type(8))) short short8;
typedef __attribute__((ext_vector_type(4))) float float4v;

__device__ __forceinline__ unsigned short f2bf(float f) {
    unsigned int u = __builtin_bit_cast(unsigned int, f);
    unsigned int r = (u + 0x7fffu + ((u >> 16) & 1u)) >> 16;  // round-nearest-even
    return (unsigned short)r;
}

// Phase 1: 4 rows/wave (float4/lane, 16-lane groups). Gathers ue/pe/ne, writes
// e1*SCALE5 row-major (A-frags) and g = e1+e2 in MFMA-B-fragment-swizzled tile
// order: tile t = 64 g-rows stored as (ct,ks) sub-blocks of 512 elems, lane-
// major (lane = q*16+rowsel holds 8 consecutive k). phase2 then loads b-frags
// from ONE base + lane*16 + small const offsets -> no per-load address math.
// Also: per-row pos/bpr/reg, zero total[] and out[0..2].
// grid: 512 blocks x 256 thr = 2048 waves = 8192 rows.
__global__ __launch_bounds__(256) void phase1(
    const float* __restrict__ utab,
    const float* __restrict__ itab,
    const int* __restrict__ user, const int* __restrict__ posi,
    const int* __restrict__ negi,
    unsigned short* __restrict__ e1_out, unsigned short* __restrict__ g_sw,
    float* __restrict__ pos_score, float* __restrict__ row_bpr,
    float* __restrict__ row_reg, float* __restrict__ total,
    float* __restrict__ out)
{
    const int tid = blockIdx.x * 256 + threadIdx.x;
    if (tid < BATCH) total[tid] = 0.0f;   // done before phase2 (stream order)
    if (tid < 3) out[tid] = 0.0f;         // phase3 atomically accumulates

    const int lane = threadIdx.x & 63;
    const int l16  = lane & 15;
    const int r    = (tid >> 6) * 4 + (lane >> 4);

    const int ui = user[r], pi = posi[r], ni = negi[r];
    const float4 u = *(const float4*)&utab[(size_t)ui * DIM + l16 * 4];
    const float4 p = *(const float4*)&itab[(size_t)pi * DIM + l16 * 4];
    const float4 n = *(const float4*)&itab[(size_t)ni * DIM + l16 * 4];

    float up = u.x*p.x + u.y*p.y + u.z*p.z + u.w*p.w;
    float un = u.x*n.x + u.y*n.y + u.z*n.z + u.w*n.w;
    float uu = u.x*u.x + u.y*u.y + u.z*u.z + u.w*u.w;
    float pp = p.x*p.x + p.y*p.y + p.z*p.z + p.w*p.w;
    float nn = n.x*n.x + n.y*n.y + n.z*n.z + n.w*n.w;
    #pragma unroll
    for (int off = 1; off < 16; off <<= 1) {   // reduce within 16-lane group
        up += __shfl_xor(up, off);
        un += __shfl_xor(un, off);
        uu += __shfl_xor(uu, off);
        pp += __shfl_xor(pp, off);
        nn += __shfl_xor(nn, off);
    }
    const float ia = 1.0f / fmaxf(sqrtf(uu), 1e-12f);   // e1 = u * ia
    const float ib = 1.0f / fmaxf(sqrtf(pp), 1e-12f);   // e2 = p * ib
    const float sa = SCALE5 * ia;

    union { unsigned short h[4]; uint2 v; } pa, pg;
    pa.h[0] = f2bf(u.x * sa); pa.h[1] = f2bf(u.y * sa);
    pa.h[2] = f2bf(u.z * sa); pa.h[3] = f2bf(u.w * sa);
    pg.h[0] = f2bf(u.x * ia + p.x * ib); pg.h[1] = f2bf(u.y * ia + p.y * ib);
    pg.h[2] = f2bf(u.z * ia + p.z * ib); pg.h[3] = f2bf(u.w * ia + p.w * ib);

    *(uint2*)&e1_out[r * DIM + l16 * 4] = pa.v;   // row-major (A-frags)

    // swizzled g write: lane l16 covers k in [l16*4, l16*4+4)
    {
        const int t = r >> 6, m = r & 63;
        const int ct = m >> 4, rsel = m & 15;
        const int ks = l16 >> 3, q = (l16 & 7) >> 1, half = l16 & 1;
        const int off = t * 4096 + (ct * 2 + ks) * 512 + (q * 16 + rsel) * 8 + half * 4;
        *(uint2*)&g_sw[off] = pg.v;
    }

    if (l16 == 0) {
        const float sim = up * (ia * ib);
        pos_score[r] = __expf(sim * TINV) + __expf(fmaxf(sim - MARGIN, 0.0f) * TINV);
        const float x = up - un;   // pos - neg (raw embeddings)
        row_bpr[r] = fmaxf(-x, 0.0f) + __logf(1.0f + __expf(-fabsf(x)));
        row_reg[r] = uu + pp + nn;
    }
}

// Phase 2: total[i] = sum_j f(e1_i . g_j) via bf16 MFMA, fused epilogue.
// A pre-scaled by 5*log2e so t = acc, e = 2^t (raw v_exp_f32), and
// f = e + max(e*e^-4, 1) = max(e*(1+e^-4), e+1).
// Each wave: 64 rows x 256 cols (rt=4 -> b-frags feed 4x the MFMAs of R6,
// halving L2 b-traffic). b-loads come from the swizzled-tile layout: one
// base pointer per 64-col tile + lane*16 + {0..7}*1024 const offsets.
// grid (128 row-stripes, 8 col-slices) x 256 thr (4 waves).
__global__ __launch_bounds__(256) void phase2(
    const unsigned short* __restrict__ e1,
    const unsigned short* __restrict__ g_sw,
    float* __restrict__ total)
{
    const int w = threadIdx.x >> 6;         // wave in block
    const int lane = threadIdx.x & 63;
    const int r0 = blockIdx.x * 64;
    const int rowsel = lane & 15;
    const int kbase = (lane >> 4) * 8;      // A-frag: [m=lane&15][k=quad*8+j]

    short8 a[4][2];
    #pragma unroll
    for (int rt = 0; rt < 4; rt++)
        #pragma unroll
        for (int ks = 0; ks < 2; ks++)
            a[rt][ks] = *(const short8*)&e1[(r0 + rt * 16 + rowsel) * DIM + ks * 32 + kbase];

    float rowacc[4][4];
    #pragma unroll
    for (int rt = 0; rt < 4; rt++)
        #pragma unroll
        for (int q = 0; q < 4; q++) rowacc[rt][q] = 0.0f;

    const char* gbase = (const char*)g_sw + (size_t)lane * 16;

    for (int it = 0; it < 4; it++) {
        const int t = blockIdx.y * 16 + w * 4 + it;     // 64-col tile index
        const char* bp = gbase + (size_t)t * 8192;
        short8 b[4][2];
        #pragma unroll
        for (int ct = 0; ct < 4; ct++)
            #pragma unroll
            for (int ks = 0; ks < 2; ks++)
                b[ct][ks] = *(const short8*)(bp + (ct * 2 + ks) * 1024);

        #pragma unroll
        for (int rt = 0; rt < 4; rt++) {
            #pragma unroll
            for (int ct = 0; ct < 4; ct++) {
                float4v acc = {0.0f, 0.0f, 0.0f, 0.0f};
                acc = __builtin_amdgcn_mfma_f32_16x16x32_bf16(a[rt][0], b[ct][0], acc, 0, 0, 0);
                acc = __builtin_amdgcn_mfma_f32_16x16x32_bf16(a[rt][1], b[ct][1], acc, 0, 0, 0);
                #pragma unroll
                for (int q = 0; q < 4; q++) {
                    const float e = __builtin_amdgcn_exp2f(acc[q]);  // raw v_exp_f32
                    rowacc[rt][q] += fmaxf(e * CGT, e + 1.0f);
                }
            }
        }
    }

    // reduce across the 16 column-lanes (same lane>>4 group holds same rows)
    #pragma unroll
    for (int off = 1; off < 16; off <<= 1)
        #pragma unroll
        for (int rt = 0; rt < 4; rt++)
            #pragma unroll
            for (int q = 0; q < 4; q++)
                rowacc[rt][q] += __shfl_xor(rowacc[rt][q], off);

    if ((lane & 15) == 0) {
        const int rquad = lane >> 4;  // C/D layout: row = quad*4 + q
        #pragma unroll
        for (int rt = 0; rt < 4; rt++)
            #pragma unroll
            for (int q = 0; q < 4; q++)
                atomicAdd(&total[r0 + rt * 16 + rquad * 4 + q], rowacc[rt][q]);
    }
}

// Phase 3: final reductions -> out[0..2] (float32: bpr, reg, na), atomic merge.
// 8 blocks x 1024 thr, one row per thread. out was zeroed by phase1.
__global__ __launch_bounds__(1024) void phase3(
    const float* __restrict__ pos_score, const float* __restrict__ total,
    const float* __restrict__ row_bpr, const float* __restrict__ row_reg,
    float* __restrict__ out)
{
    const int i = blockIdx.x * 1024 + threadIdx.x;
    float sb = row_bpr[i];
    float sr = row_reg[i];
    float sn = -__logf(pos_score[i] / total[i] + 1e-5f);
    #pragma unroll
    for (int off = 32; off; off >>= 1) {
        sb += __shfl_xor(sb, off);
        sr += __shfl_xor(sr, off);
        sn += __shfl_xor(sn, off);
    }
    __shared__ float rb[16], rr[16], rn[16];
    const int wid = threadIdx.x >> 6;
    if ((threadIdx.x & 63) == 0) { rb[wid] = sb; rr[wid] = sr; rn[wid] = sn; }
    __syncthreads();
    if (threadIdx.x == 0) {
        float tb = 0.0f, tr = 0.0f, tn = 0.0f;
        #pragma unroll
        for (int k = 0; k < 16; k++) { tb += rb[k]; tr += rr[k]; tn += rn[k]; }
        atomicAdd(&out[0], tb / (float)BATCH);
        atomicAdd(&out[1], LREG * 0.5f * tr / (float)BATCH);
        atomicAdd(&out[2], LGAMMA * tn / (float)BATCH);
    }
}

extern "C" void kernel_launch(void* const* d_in, const int* in_sizes, int n_in,
                              void* d_out, int out_size, void* d_ws, size_t ws_size,
                              hipStream_t stream) {
    const float* utab = (const float*)d_in[0];  // float32 [100000,64]
    const float* itab = (const float*)d_in[1];  // float32 [50000,64]
    const int* user = (const int*)d_in[2];
    const int* posi = (const int*)d_in[3];
    const int* negi = (const int*)d_in[4];

    char* ws = (char*)d_ws;
    unsigned short* e1   = (unsigned short*)ws;                              // 1 MiB
    unsigned short* g_sw = (unsigned short*)(ws + (size_t)BATCH * DIM * 2);  // 1 MiB
    float* pos_score     = (float*)(ws + 2 * (size_t)BATCH * DIM * 2);       // 32 KiB
    float* total         = pos_score + BATCH;                                // 32 KiB
    float* row_bpr       = total + BATCH;                                    // 32 KiB
    float* row_reg       = row_bpr + BATCH;                                  // 32 KiB

    phase1<<<512, 256, 0, stream>>>(utab, itab, user, posi, negi,
                                    e1, g_sw, pos_score, row_bpr, row_reg,
                                    total, (float*)d_out);
    phase2<<<dim3(128, 8), 256, 0, stream>>>(e1, g_sw, total);
    phase3<<<8, 1024, 0, stream>>>(pos_score, total, row_bpr, row_reg,
                                   (float*)d_out);
}